// Round 4
// baseline (335.266 us; speedup 1.0000x reference)
//
#include <hip/hip_runtime.h>

#define CIN   256
#define COUT  256
#define HH    56
#define WW    56
#define BATCH 32
#define KTOT  2304           // CIN * 9, ordered (kh,kw,ci)
#define HP    58
#define WP    58
#define NPIX  (BATCH*HH*WW)  // 100352
#define HWSZ  (HH*WW)        // 3136
#define KT    36             // K-tiles of 64

typedef __bf16 bf16x8 __attribute__((ext_vector_type(8)));
typedef float  f32x4  __attribute__((ext_vector_type(4)));

#define AS1 __attribute__((address_space(1)))
#define AS3 __attribute__((address_space(3)))

__device__ __forceinline__ unsigned short f2bf(float f) {
  union { float f; unsigned int u; } v; v.f = f;
  unsigned int u = v.u;
  u += 0x7fffu + ((u >> 16) & 1u);   // round-to-nearest-even
  return (unsigned short)(u >> 16);
}

__device__ __forceinline__ void async16(const void* g, void* l) {
  __builtin_amdgcn_global_load_lds((const AS1 unsigned int*)g,
                                   (AS3 unsigned int*)l, 16, 0, 0);
}

// ---- kernel 1: ternary-quantize weights, reorder OIHW -> [co][kh][kw][ci] bf16
__global__ __launch_bounds__(256) void quant_w(const float* __restrict__ w,
                                               unsigned short* __restrict__ wr) {
  int tid = blockIdx.x * 256 + threadIdx.x;
  if (tid >= COUT * KTOT) return;
  int co  = tid / KTOT;
  int rem = tid - co * KTOT;
  int tap = rem >> 8;          // kh*3+kw
  int ci  = rem & 255;
  int kh  = tap / 3;
  int kw  = tap - kh * 3;
  float v = w[((co * CIN + ci) * 3 + kh) * 3 + kw];
  float q = (fabsf(v) > 0.05f) ? ((v > 0.f) ? 1.f : -1.f) : 0.f;
  wr[tid] = f2bf(q);           // -1/0/+1 exact in bf16
}

// ---- kernel 2: x NCHW fp32 -> zero-padded NHWC bf16  Xp[n][hp][wp][ci]
#define TSTR 60
__global__ __launch_bounds__(256) void pad_nhwc(const float* __restrict__ x,
                                                unsigned short* __restrict__ xp) {
  const int nhp = blockIdx.x;            // n*58 + hp
  const int n   = nhp / HP;
  const int hp  = nhp - n * HP;
  const int ci0 = blockIdx.y * 64;
  const int t   = threadIdx.x;
  const size_t obase = (size_t)nhp * (WP * 256);

  __shared__ __align__(16) float tile[64 * TSTR];
  const bool hborder = (hp == 0) || (hp == HP - 1);

  if (!hborder) {
    const int h = hp - 1;
    #pragma unroll
    for (int it = 0; it < 4; ++it) {
      int linear = it * 256 + t;
      if (linear < 896) {                // 64 ch x 14 float4
        int cil = linear / 14;
        int w4  = linear - cil * 14;
        *(float4*)&tile[cil * TSTR + w4 * 4] =
            *(const float4*)&x[(((size_t)(n * CIN + ci0 + cil)) * HH + h) * WW + w4 * 4];
      }
    }
  }
  __syncthreads();

  #pragma unroll
  for (int it = 0; it < 2; ++it) {               // 58*8 = 464 16B-chunks
    int linear = it * 256 + t;
    if (linear < 464) {
      int wp = linear >> 3;
      int g  = linear & 7;                       // ci group of 8
      unsigned int pk[4] = {0u, 0u, 0u, 0u};
      if (!hborder && wp != 0 && wp != WP - 1) {
        #pragma unroll
        for (int j = 0; j < 4; ++j) {
          unsigned int lo = f2bf(tile[(g * 8 + 2 * j) * TSTR + (wp - 1)]);
          unsigned int hi = f2bf(tile[(g * 8 + 2 * j + 1) * TSTR + (wp - 1)]);
          pk[j] = lo | (hi << 16);
        }
      }
      uint4 v; v.x = pk[0]; v.y = pk[1]; v.z = pk[2]; v.w = pk[3];
      *(uint4*)(xp + obase + (size_t)wp * 256 + ci0 + g * 8) = v;
    }
  }
}

// ---- kernel 3: implicit GEMM, 256x256 tile, BK=64, 8 waves (2Mx4N).
// ROUND-4 RESTRUCTURE (staging-granularity theory):
//   - whole-BK regions, 128-B rows: A[buf][256 co][64 k], B[buf][256 px][64 k]
//     (4 x 32 KB = 128 KiB). Each global_load_lds now pulls 8 x 128 B
//     FULL-cache-line segments per wave (was 16 x 64 B half-lines).
//   - XOR swizzle chunk^=(row&7) (st_16x32 analog for 128-B rows), applied
//     on the GLOBAL source at stage time + same XOR on ds_read (rule #21).
//     Conflict math: per wave 64 lanes -> 8 granules x 8 lanes uniform =
//     conflict-free for ds_read_b128.
//   - distance-1 prefetch: tile kk+1 staged into buf^1 spread 3/3/2 over
//     phases 1-3 of tile kk; ONE vmcnt(0) drain at end of phase 4 (newest
//     outstanding load is >=1 full phase old -> near-free wait), before the
//     trailing barrier (cross-wave safe).
//   - phases per tile: (kq,mh) in {0,1}^2; phase = 4/8 ds_read_b128 + stages
//     + barrier + lgkmcnt(0) + sched_barrier + setprio + 16 MFMA + barrier.
// M/N fragment mapping and epilogue identical to the verified r3 kernel.

#define NOWAIT (void)0
#define VM0 asm volatile("s_waitcnt vmcnt(0)" ::: "memory")

#define SA(bn_, s_) async16(Wr + koW + aSrc##s_, smem + (bn_) + (s_)*8192 + t*16)
#define SB(bn_, s_) async16(Xp + koX + bSrc[s_], smem + 65536 + (bn_) + (s_)*8192 + t*16)

#define PHASE(ab_, kq_, mh_, WAITE, ...) do {                                 \
  __VA_ARGS__;                                                                \
  bf16x8 af_[4];                                                              \
  _Pragma("unroll")                                                           \
  for (int mt = 0; mt < 4; ++mt)                                              \
    af_[mt] = *(const bf16x8*)(smem + (ab_) + rA + (mh_)*8192 + mt*2048 +     \
                               ((kq_) ? cX1 : cX0));                          \
  if ((mh_) == 0) {                                                           \
    _Pragma("unroll")                                                         \
    for (int nt = 0; nt < 4; ++nt)                                            \
      bfr[nt] = *(const bf16x8*)(smem + 65536 + (ab_) + rB + nt*2048 +        \
                                 ((kq_) ? cX1 : cX0));                        \
  }                                                                           \
  __builtin_amdgcn_s_barrier();                                               \
  asm volatile("s_waitcnt lgkmcnt(0)" ::: "memory");                          \
  __builtin_amdgcn_sched_barrier(0);                                          \
  __builtin_amdgcn_s_setprio(1);                                              \
  _Pragma("unroll")                                                           \
  for (int mt = 0; mt < 4; ++mt)                                              \
    _Pragma("unroll")                                                         \
    for (int nt = 0; nt < 4; ++nt)                                            \
      acc[(mh_)*4+mt][nt] = __builtin_amdgcn_mfma_f32_16x16x32_bf16(          \
          af_[mt], bfr[nt], acc[(mh_)*4+mt][nt], 0, 0, 0);                    \
  __builtin_amdgcn_s_setprio(0);                                              \
  WAITE;                                                                      \
  __builtin_amdgcn_s_barrier();                                               \
} while (0)

__global__ __launch_bounds__(512, 2) void conv_gemm(
    const unsigned short* __restrict__ Wr,
    const unsigned short* __restrict__ Xp,
    const float* __restrict__ bias,
    float* __restrict__ out) {
  extern __shared__ char smem[];   // 131072 B: A0,A1,B0,B1 regions of 32 KB

  const int t    = threadIdx.x;
  const int lane = t & 63;
  const int wv   = t >> 6;        // 0..7
  const int wm   = wv >> 2;       // 0..1  (co half)
  const int wn   = wv & 3;        // 0..3  (pixel quarter)
  const int l15  = lane & 15;
  const int quad = lane >> 4;

  // T1: bijective XCD swizzle over 392 = 8 * 49 blocks
  const int bid = blockIdx.x;
  const int pb  = (bid & 7) * 49 + (bid >> 3);
  const int p0  = pb * 256;

  // staging map: thread t -> row (t>>3) (+64 per sweep), phys chunk t&7,
  // logical chunk = (t&7) ^ (row&7)   [T2 inverse on global source]
  const int srow  = t >> 3;                      // 0..63
  const int sclog = (t & 7) ^ (srow & 7);

  const size_t aSrc0 = (size_t)srow * KTOT + sclog * 8;
  const size_t aSrc1 = aSrc0 + (size_t)64  * KTOT;
  const size_t aSrc2 = aSrc0 + (size_t)128 * KTOT;
  const size_t aSrc3 = aSrc0 + (size_t)192 * KTOT;

  size_t bSrc[4];
  #pragma unroll
  for (int s = 0; s < 4; ++s) {
    int p = p0 + s * 64 + srow;
    int n = p / HWSZ; int hw = p - n * HWSZ;
    int h = hw / WW;  int w = hw - h * WW;
    bSrc[s] = ((size_t)((n * HP + h) * WP + w)) * 256 + sclog * 8;
  }

  // fragment-read invariants: row*128 bytes; chunk = (kq*4+quad) ^ (row&7),
  // row&7 == lane&7 for all fragment rows (bases are multiples of 16).
  const int rA  = (wm * 128 + l15) * 128;   // + mh*8192 + mt*2048
  const int rB  = (wn * 64  + l15) * 128;   // + nt*2048
  const int cX0 = ((quad      ^ (lane & 7)) * 16);
  const int cX1 = (((4 + quad) ^ (lane & 7)) * 16);

  f32x4 acc[8][4];
  #pragma unroll
  for (int i = 0; i < 8; ++i)
    #pragma unroll
    for (int j = 0; j < 4; ++j)
      acc[i][j] = (f32x4){0.f, 0.f, 0.f, 0.f};
  bf16x8 bfr[4];

  // ---- prologue: stage tile 0 into buf 0 (tap (0,0), ci-base 0)
  {
    const size_t koW = 0;
    const size_t koX = 0;
    SA(0, 0); SA(0, 1); SA(0, 2); SA(0, 3);
    SB(0, 0); SB(0, 1); SB(0, 2); SB(0, 3);
  }
  VM0;
  __builtin_amdgcn_s_barrier();

  // ---- main: tiles 0..34, each stages tile kk+1 (3/3/2 over phases 1-3)
  #pragma unroll 1
  for (int kk = 0; kk < 35; ++kk) {
    const int ab = (kk & 1) << 15;       // current buffer base (A side)
    const int bn = 32768 - ab;           // next buffer base
    const int kn = kk + 1;
    const size_t koW = (size_t)kn * 64;
    const int tapn = kn >> 2;
    const int khn  = tapn / 3;
    const int kwn  = tapn - khn * 3;
    const size_t koX = (size_t)((khn * WP + kwn) * 256 + ((kn & 3) << 6));

    PHASE(ab, 0, 0, NOWAIT, SA(bn, 0); SA(bn, 1); SA(bn, 2));
    PHASE(ab, 0, 1, NOWAIT, SA(bn, 3); SB(bn, 0); SB(bn, 1));
    PHASE(ab, 1, 0, NOWAIT, SB(bn, 2); SB(bn, 3));
    PHASE(ab, 1, 1, VM0,    NOWAIT);
  }
  // ---- tile 35 (buf 1): nothing left to stage
  {
    PHASE(32768, 0, 0, NOWAIT, NOWAIT);
    PHASE(32768, 0, 1, NOWAIT, NOWAIT);
    PHASE(32768, 1, 0, NOWAIT, NOWAIT);
    PHASE(32768, 1, 1, NOWAIT, NOWAIT);
  }

  // ---- epilogue: C/D layout col = lane&15 (pixel), row = quad*4+reg (co)
  float bv[8][4];
  #pragma unroll
  for (int m = 0; m < 8; ++m)
    #pragma unroll
    for (int r = 0; r < 4; ++r)
      bv[m][r] = bias[wm * 128 + m * 16 + quad * 4 + r];

  #pragma unroll
  for (int nt = 0; nt < 4; ++nt) {
    const int p  = p0 + wn * 64 + nt * 16 + l15;
    const int np = p / HWSZ;
    const int hw = p - np * HWSZ;
    const size_t obase = (size_t)np * (COUT * HWSZ) + hw;
    #pragma unroll
    for (int m = 0; m < 8; ++m) {
      const int co = wm * 128 + m * 16 + quad * 4;
      #pragma unroll
      for (int r = 0; r < 4; ++r)
        out[obase + (size_t)(co + r) * HWSZ] = acc[m][nt][r] + bv[m][r];
    }
  }
}

extern "C" void kernel_launch(void* const* d_in, const int* in_sizes, int n_in,
                              void* d_out, int out_size, void* d_ws, size_t ws_size,
                              hipStream_t stream) {
  const float* x    = (const float*)d_in[0];
  const float* w    = (const float*)d_in[1];
  const float* bias = (const float*)d_in[2];
  float* out        = (float*)d_out;

  // workspace layout: Xp (padded NHWC bf16) then Wr (reordered ternary bf16)
  unsigned short* xp = (unsigned short*)d_ws;                       // 55,115,776 B
  unsigned short* wr = (unsigned short*)((char*)d_ws + 55115776);   //  1,179,648 B

  quant_w<<<dim3((COUT * KTOT) / 256), dim3(256), 0, stream>>>(w, wr);
  pad_nhwc<<<dim3(BATCH * HP, 4), dim3(256), 0, stream>>>(x, xp);

  (void)hipFuncSetAttribute((const void*)conv_gemm,
                            hipFuncAttributeMaxDynamicSharedMemorySize, 131072);
  conv_gemm<<<dim3(392), dim3(512), 131072, stream>>>(wr, xp, bias, out);
}

// Round 5
// 331.869 us; speedup vs baseline: 1.0102x; 1.0102x over previous
//
#include <hip/hip_runtime.h>

#define CIN   256
#define COUT  256
#define HH    56
#define WW    56
#define BATCH 32
#define KTOT  2304           // CIN * 9, ordered (kh,kw,ci)
#define HP    58
#define WP    58
#define NPIX  (BATCH*HH*WW)  // 100352
#define HWSZ  (HH*WW)        // 3136

typedef __bf16 bf16x8 __attribute__((ext_vector_type(8)));
typedef float  f32x4  __attribute__((ext_vector_type(4)));

#define AS1 __attribute__((address_space(1)))
#define AS3 __attribute__((address_space(3)))

__device__ __forceinline__ unsigned short f2bf(float f) {
  union { float f; unsigned int u; } v; v.f = f;
  unsigned int u = v.u;
  u += 0x7fffu + ((u >> 16) & 1u);   // round-to-nearest-even
  return (unsigned short)(u >> 16);
}

__device__ __forceinline__ void async16(const void* g, void* l) {
  __builtin_amdgcn_global_load_lds((const AS1 unsigned int*)g,
                                   (AS3 unsigned int*)l, 16, 0, 0);
}

// ---- kernel 1: ternary-quantize weights, reorder OIHW -> [co][kh][kw][ci] bf16
__global__ __launch_bounds__(256) void quant_w(const float* __restrict__ w,
                                               unsigned short* __restrict__ wr) {
  int tid = blockIdx.x * 256 + threadIdx.x;
  if (tid >= COUT * KTOT) return;
  int co  = tid / KTOT;
  int rem = tid - co * KTOT;
  int tap = rem >> 8;          // kh*3+kw
  int ci  = rem & 255;
  int kh  = tap / 3;
  int kw  = tap - kh * 3;
  float v = w[((co * CIN + ci) * 3 + kh) * 3 + kw];
  float q = (fabsf(v) > 0.05f) ? ((v > 0.f) ? 1.f : -1.f) : 0.f;
  wr[tid] = f2bf(q);           // -1/0/+1 exact in bf16
}

// ---- kernel 2: x NCHW fp32 -> zero-padded NHWC bf16  Xp[n][hp][wp][ci]
#define TSTR 60
__global__ __launch_bounds__(256) void pad_nhwc(const float* __restrict__ x,
                                                unsigned short* __restrict__ xp) {
  const int nhp = blockIdx.x;            // n*58 + hp
  const int n   = nhp / HP;
  const int hp  = nhp - n * HP;
  const int ci0 = blockIdx.y * 64;
  const int t   = threadIdx.x;
  const size_t obase = (size_t)nhp * (WP * 256);

  __shared__ __align__(16) float tile[64 * TSTR];
  const bool hborder = (hp == 0) || (hp == HP - 1);

  if (!hborder) {
    const int h = hp - 1;
    #pragma unroll
    for (int it = 0; it < 4; ++it) {
      int linear = it * 256 + t;
      if (linear < 896) {                // 64 ch x 14 float4
        int cil = linear / 14;
        int w4  = linear - cil * 14;
        *(float4*)&tile[cil * TSTR + w4 * 4] =
            *(const float4*)&x[(((size_t)(n * CIN + ci0 + cil)) * HH + h) * WW + w4 * 4];
      }
    }
  }
  __syncthreads();

  #pragma unroll
  for (int it = 0; it < 2; ++it) {               // 58*8 = 464 16B-chunks
    int linear = it * 256 + t;
    if (linear < 464) {
      int wp = linear >> 3;
      int g  = linear & 7;                       // ci group of 8
      unsigned int pk[4] = {0u, 0u, 0u, 0u};
      if (!hborder && wp != 0 && wp != WP - 1) {
        #pragma unroll
        for (int j = 0; j < 4; ++j) {
          unsigned int lo = f2bf(tile[(g * 8 + 2 * j) * TSTR + (wp - 1)]);
          unsigned int hi = f2bf(tile[(g * 8 + 2 * j + 1) * TSTR + (wp - 1)]);
          pk[j] = lo | (hi << 16);
        }
      }
      uint4 v; v.x = pk[0]; v.y = pk[1]; v.z = pk[2]; v.w = pk[3];
      *(uint4*)(xp + obase + (size_t)wp * 256 + ci0 + g * 8) = v;
    }
  }
}

// ---- kernel 3: implicit GEMM, CO-RESIDENCY RESTRUCTURE (round 5).
// 128x128 tile, 4 waves (2Mx2N), BK=32, TRIPLE-buffered 48 KiB LDS ->
// 3 blocks/CU co-resident (12 waves/CU): independent blocks fill each
// other's barrier/lgkmcnt bubbles (the ~575 cyc/phase exposure measured
// r2-r4) AND pack the grid tail (1568 blocks vs 392: granule 0.65 blk/CU).
//   - distance-2 prefetch, counted vmcnt(4): stage tile k+2 in phase k,
//     wait (end of phase k) for tile k+1's 4 loads, leaving k+2's in
//     flight. ~2 phases (>1800 cyc) of slack per load -> covers HBM.
//   - r3-verified XOR swizzle for 64-B rows: chunk ^= (row>>1)&3 (counter
//     showed 0 conflicts). Inverse-applied on the global source (rule #21).
//   - buffers statically indexed via 3-phase unroll (rule #20).
//   - T1: bijective XCD swizzle over 1568 = 8*196, co-pairs adjacent so
//     the two blocks sharing a pixel-panel land on the same XCD's L2.

#define NOWAIT (void)0
#define VM4 asm volatile("s_waitcnt vmcnt(4)" ::: "memory")
#define VM0 asm volatile("s_waitcnt vmcnt(0)" ::: "memory")

// stage tile kn_ (A 8 KB + B 8 KB) into buffer buf_: 4 global_load_lds
#define STAGE4(buf_, kn_) do {                                                \
  const int kn__ = (kn_);                                                     \
  const size_t koW_ = (size_t)kn__ << 5;                                      \
  const int tap_ = kn__ >> 3;                                                 \
  const int kh_  = tap_ / 3;                                                  \
  const int kw_  = tap_ - kh_ * 3;                                            \
  const size_t koX_ = (size_t)((kh_ * WP + kw_) * 256 + ((kn__ & 7) << 5));   \
  char* da_ = smem + (buf_) * 8192 + t * 16;                                  \
  char* db_ = smem + 24576 + (buf_) * 8192 + t * 16;                          \
  async16(Wr + koW_ + aSrc0, da_);                                            \
  async16(Wr + koW_ + aSrc1, da_ + 4096);                                     \
  async16(Xp + koX_ + bSrc0, db_);                                            \
  async16(Xp + koX_ + bSrc1, db_ + 4096);                                     \
} while (0)

#define PHASE(buf_, WAITE, ...) do {                                          \
  __VA_ARGS__;                                                                \
  bf16x8 af_[4], bf_[4];                                                      \
  _Pragma("unroll")                                                           \
  for (int mt = 0; mt < 4; ++mt)                                              \
    af_[mt] = *(const bf16x8*)(smem + (buf_) * 8192 + rdA + mt * 1024);       \
  _Pragma("unroll")                                                           \
  for (int nt = 0; nt < 4; ++nt)                                              \
    bf_[nt] = *(const bf16x8*)(smem + 24576 + (buf_) * 8192 + rdB + nt * 1024);\
  __builtin_amdgcn_s_barrier();                                               \
  asm volatile("s_waitcnt lgkmcnt(0)" ::: "memory");                          \
  __builtin_amdgcn_sched_barrier(0);                                          \
  __builtin_amdgcn_s_setprio(1);                                              \
  _Pragma("unroll")                                                           \
  for (int mt = 0; mt < 4; ++mt)                                              \
    _Pragma("unroll")                                                         \
    for (int nt = 0; nt < 4; ++nt)                                            \
      acc[mt][nt] = __builtin_amdgcn_mfma_f32_16x16x32_bf16(                  \
          af_[mt], bf_[nt], acc[mt][nt], 0, 0, 0);                            \
  __builtin_amdgcn_s_setprio(0);                                              \
  WAITE;                                                                      \
  __builtin_amdgcn_s_barrier();                                               \
} while (0)

__global__ __launch_bounds__(256, 3) void conv_gemm(
    const unsigned short* __restrict__ Wr,
    const unsigned short* __restrict__ Xp,
    const float* __restrict__ bias,
    float* __restrict__ out) {
  extern __shared__ char smem[];   // 49152 B: A[3] @ 0, B[3] @ 24576 (8 KB each)

  const int t    = threadIdx.x;
  const int lane = t & 63;
  const int wv   = t >> 6;        // 0..3
  const int wm   = wv >> 1;       // co half (64)
  const int wn   = wv & 1;        // px half (64)
  const int l15  = lane & 15;
  const int quad = lane >> 4;

  // T1: bijective XCD swizzle over 1568 = 8*196; co-pairs adjacent.
  const int bid = blockIdx.x;
  const int nf  = (bid & 7) * 196 + (bid >> 3);
  const int cob = nf & 1;
  const int pb  = nf >> 1;        // [0,784): 98 contiguous per XCD
  const int co0 = cob * 128;
  const int p0  = pb * 128;

  // staging map: thread t -> row t>>2 (0..63; +64 second sweep), phys chunk
  // t&3, logical chunk = (t&3) ^ ((row>>1)&3)  [T2 inverse on global source;
  // row+64 preserves bits 1..2? 64>>1=32 ≡ 0 mod 4 -> yes]
  const int srow = t >> 2;
  const int schk = (t & 3) ^ ((srow >> 1) & 3);

  const size_t aSrc0 = (size_t)(co0 + srow) * KTOT + schk * 8;
  const size_t aSrc1 = aSrc0 + (size_t)64 * KTOT;

  const int pA = p0 + srow;
  const int pB = pA + 64;
  const int nA = pA / HWSZ;  const int hwA = pA - nA * HWSZ;
  const int hA = hwA / WW;   const int wA  = hwA - hA * WW;
  const int nB = pB / HWSZ;  const int hwB = pB - nB * HWSZ;
  const int hB = hwB / WW;   const int wB  = hwB - hB * WW;
  const size_t bSrc0 = ((size_t)((nA * HP + hA) * WP + wA)) * 256 + schk * 8;
  const size_t bSrc1 = ((size_t)((nB * HP + hB) * WP + wB)) * 256 + schk * 8;

  // read side: row*64 B; logical k-quad 'quad' -> phys chunk quad^((row>>1)&3)
  // (row bits 1..2 == l15 bits 1..2 since all row bases are multiples of 16)
  const int rchk = (quad ^ ((l15 >> 1) & 3)) * 16;
  const int rdA  = (wm * 64 + l15) * 64 + rchk;   // + mt*1024
  const int rdB  = (wn * 64 + l15) * 64 + rchk;   // + nt*1024

  f32x4 acc[4][4];
  #pragma unroll
  for (int i = 0; i < 4; ++i)
    #pragma unroll
    for (int j = 0; j < 4; ++j)
      acc[i][j] = (f32x4){0.f, 0.f, 0.f, 0.f};

  // ---- prologue: stage tiles 0,1 into bufs 0,1; wait tile 0 (vmcnt(4))
  STAGE4(0, 0);
  STAGE4(1, 1);
  VM4;
  __builtin_amdgcn_s_barrier();

  // ---- main: 72 K-tiles of 32. Phase k: compute buf k%3, stage k+2 into
  // (k+2)%3, wait tile k+1's loads (vmcnt(4)). Statically unrolled by 3.
  #pragma unroll 1
  for (int it = 0; it < 23; ++it) {
    const int k0 = 3 * it;
    PHASE(0, VM4, STAGE4(2, k0 + 2));
    PHASE(1, VM4, STAGE4(0, k0 + 3));
    PHASE(2, VM4, STAGE4(1, k0 + 4));
  }
  PHASE(0, VM4, STAGE4(2, 71));    // k=69, stage last tile
  PHASE(1, VM0, NOWAIT);           // k=70, drain tile 71
  PHASE(2, NOWAIT, NOWAIT);        // k=71

  // ---- epilogue: C/D layout col = lane&15 (pixel), row = quad*4+reg (co)
  float bv[4][4];
  #pragma unroll
  for (int mt = 0; mt < 4; ++mt)
    #pragma unroll
    for (int r = 0; r < 4; ++r)
      bv[mt][r] = bias[co0 + wm * 64 + mt * 16 + quad * 4 + r];

  #pragma unroll
  for (int nt = 0; nt < 4; ++nt) {
    const int p  = p0 + wn * 64 + nt * 16 + l15;
    const int np = p / HWSZ;
    const int hw = p - np * HWSZ;
    const size_t obase = (size_t)np * (COUT * HWSZ) + hw;
    #pragma unroll
    for (int mt = 0; mt < 4; ++mt) {
      const int co = co0 + wm * 64 + mt * 16 + quad * 4;
      #pragma unroll
      for (int r = 0; r < 4; ++r)
        out[obase + (size_t)(co + r) * HWSZ] = acc[mt][nt][r] + bv[mt][r];
    }
  }
}

extern "C" void kernel_launch(void* const* d_in, const int* in_sizes, int n_in,
                              void* d_out, int out_size, void* d_ws, size_t ws_size,
                              hipStream_t stream) {
  const float* x    = (const float*)d_in[0];
  const float* w    = (const float*)d_in[1];
  const float* bias = (const float*)d_in[2];
  float* out        = (float*)d_out;

  // workspace layout: Xp (padded NHWC bf16) then Wr (reordered ternary bf16)
  unsigned short* xp = (unsigned short*)d_ws;                       // 55,115,776 B
  unsigned short* wr = (unsigned short*)((char*)d_ws + 55115776);   //  1,179,648 B

  quant_w<<<dim3((COUT * KTOT) / 256), dim3(256), 0, stream>>>(w, wr);
  pad_nhwc<<<dim3(BATCH * HP, 4), dim3(256), 0, stream>>>(x, xp);

  (void)hipFuncSetAttribute((const void*)conv_gemm,
                            hipFuncAttributeMaxDynamicSharedMemorySize, 49152);
  conv_gemm<<<dim3(1568), dim3(256), 49152, stream>>>(wr, xp, bias, out);
}

// Round 6
// 324.129 us; speedup vs baseline: 1.0344x; 1.0239x over previous
//
#include <hip/hip_runtime.h>

#define CIN   256
#define COUT  256
#define HH    56
#define WW    56
#define BATCH 32
#define KTOT  2304           // CIN * 9, ordered (kh,kw,ci)
#define HP    58
#define WP    58
#define NPIX  (BATCH*HH*WW)  // 100352
#define HWSZ  (HH*WW)        // 3136
#define BN    224            // pixel tile -> 448 blocks = 1.75 * 256 CUs
#define NBLK  (NPIX/BN)      // 448

typedef __bf16 bf16x8 __attribute__((ext_vector_type(8)));
typedef float  f32x4  __attribute__((ext_vector_type(4)));

#define AS1 __attribute__((address_space(1)))
#define AS3 __attribute__((address_space(3)))

__device__ __forceinline__ unsigned short f2bf(float f) {
  union { float f; unsigned int u; } v; v.f = f;
  unsigned int u = v.u;
  u += 0x7fffu + ((u >> 16) & 1u);   // round-to-nearest-even
  return (unsigned short)(u >> 16);
}

__device__ __forceinline__ void async16(const void* g, void* l) {
  __builtin_amdgcn_global_load_lds((const AS1 unsigned int*)g,
                                   (AS3 unsigned int*)l, 16, 0, 0);
}

// ---- kernel 1 (fused): blocks [0,2304) quantize weights; rest do pad/NHWC.
//   quant: OIHW fp32 -> [co][kh][kw][ci] ternary bf16
//   pad:   x NCHW fp32 -> zero-padded NHWC bf16  Xp[n][hp][wp][ci]
// pack-phase bank fix: read order rotated jr=(j+g)&3 so the 8 g-lanes of a
// wp hit 4 distinct bank groups (2-way = free) instead of 8-way.
#define TSTR 60
#define QBLKS 2304
__global__ __launch_bounds__(256) void prep(const float* __restrict__ w,
                                            unsigned short* __restrict__ wr,
                                            const float* __restrict__ x,
                                            unsigned short* __restrict__ xp) {
  const int bx = blockIdx.x;
  if (bx < QBLKS) {
    int tid = bx * 256 + threadIdx.x;       // < COUT*KTOT = 589824
    int co  = tid / KTOT;
    int rem = tid - co * KTOT;
    int tap = rem >> 8;          // kh*3+kw
    int ci  = rem & 255;
    int kh  = tap / 3;
    int kw  = tap - kh * 3;
    float v = w[((co * CIN + ci) * 3 + kh) * 3 + kw];
    float q = (fabsf(v) > 0.05f) ? ((v > 0.f) ? 1.f : -1.f) : 0.f;
    wr[tid] = f2bf(q);           // -1/0/+1 exact in bf16
    return;
  }
  const int pbx = bx - QBLKS;            // [0, 1856*4)
  const int nhp = pbx >> 2;              // n*58 + hp
  const int n   = nhp / HP;
  const int hp  = nhp - n * HP;
  const int ci0 = (pbx & 3) << 6;
  const int t   = threadIdx.x;
  const size_t obase = (size_t)nhp * (WP * 256);

  __shared__ __align__(16) float tile[64 * TSTR];
  const bool hborder = (hp == 0) || (hp == HP - 1);

  if (!hborder) {
    const int h = hp - 1;
    #pragma unroll
    for (int it = 0; it < 4; ++it) {
      int linear = it * 256 + t;
      if (linear < 896) {                // 64 ch x 14 float4
        int cil = linear / 14;
        int w4  = linear - cil * 14;
        *(float4*)&tile[cil * TSTR + w4 * 4] =
            *(const float4*)&x[(((size_t)(n * CIN + ci0 + cil)) * HH + h) * WW + w4 * 4];
      }
    }
  }
  __syncthreads();

  #pragma unroll
  for (int it = 0; it < 2; ++it) {               // 58*8 = 464 16B-chunks
    int linear = it * 256 + t;
    if (linear < 464) {
      int wp = linear >> 3;
      int g  = linear & 7;                       // ci group of 8
      unsigned int pk[4] = {0u, 0u, 0u, 0u};
      if (!hborder && wp != 0 && wp != WP - 1) {
        #pragma unroll
        for (int j = 0; j < 4; ++j) {
          int jr = (j + g) & 3;                  // bank-rotation (2-way, free)
          unsigned int lo = f2bf(tile[(g * 8 + 2 * jr) * TSTR + (wp - 1)]);
          unsigned int hi = f2bf(tile[(g * 8 + 2 * jr + 1) * TSTR + (wp - 1)]);
          pk[jr] = lo | (hi << 16);
        }
      }
      uint4 v; v.x = pk[0]; v.y = pk[1]; v.z = pk[2]; v.w = pk[3];
      *(uint4*)(xp + obase + (size_t)wp * 256 + ci0 + g * 8) = v;
    }
  }
}

// ---- kernel 2: implicit GEMM, 256co x 224px tile, BK=32, 8 waves (4Mx2N),
// wave = 64co x 112px -> per K-32 phase: 4 A-frags + 7 B-frags, 28 MFMA
// (0.39 frag/MFMA operand intensity; LDS demand ~133 B/cyc at full pipe).
// 448 blocks = 1.75 rounds -> 87.5% grid efficiency (vs 76.6% at 392).
// TRIPLE-buffered (3 x 32 KB = 96 KiB), dist-2 prefetch, counted vmcnt(4)
// (r5-proven schedule), r3-verified XOR swizzle chunk^=(row>>1)&3 (0
// conflicts measured). B region padded to 256 rows for uniform 2-sweep
// staging; garbage rows 224-255 stay inside d_ws and are never read by MFMA.

#define NOWAIT (void)0
#define VM4 asm volatile("s_waitcnt vmcnt(4)" ::: "memory")
#define VM0 asm volatile("s_waitcnt vmcnt(0)" ::: "memory")

// stage K-tile kn_ (A 16 KB + B 16 KB) into buffer buf_: 4 global_load_lds
#define STAGE4(buf_, kn_) do {                                                \
  const int kn__ = (kn_);                                                     \
  const size_t koW_ = (size_t)kn__ << 5;                                      \
  const int tap_ = kn__ >> 3;                                                 \
  const int kh_  = tap_ / 3;                                                  \
  const int kw_  = tap_ - kh_ * 3;                                            \
  const size_t koX_ = (size_t)((kh_ * WP + kw_) * 256 + ((kn__ & 7) << 5));   \
  char* da_ = smem + (buf_) * 32768 + t * 16;                                 \
  char* db_ = smem + (buf_) * 32768 + 16384 + t * 16;                         \
  async16(Wr + koW_ + aSrc0, da_);                                            \
  async16(Wr + koW_ + aSrc1, da_ + 8192);                                     \
  async16(Xp + koX_ + bSrc0, db_);                                            \
  async16(Xp + koX_ + bSrc1, db_ + 8192);                                     \
} while (0)

#define PHASE(buf_, WAITE, ...) do {                                          \
  __VA_ARGS__;                                                                \
  bf16x8 af_[4], bf_[7];                                                      \
  _Pragma("unroll")                                                           \
  for (int mt = 0; mt < 4; ++mt)                                              \
    af_[mt] = *(const bf16x8*)(smem + (buf_) * 32768 + rdA + mt * 1024);      \
  _Pragma("unroll")                                                           \
  for (int nt = 0; nt < 7; ++nt)                                              \
    bf_[nt] = *(const bf16x8*)(smem + (buf_) * 32768 + 16384 + rdB + nt * 1024);\
  __builtin_amdgcn_s_barrier();                                               \
  asm volatile("s_waitcnt lgkmcnt(0)" ::: "memory");                          \
  __builtin_amdgcn_sched_barrier(0);                                          \
  __builtin_amdgcn_s_setprio(1);                                              \
  _Pragma("unroll")                                                           \
  for (int mt = 0; mt < 4; ++mt)                                              \
    _Pragma("unroll")                                                         \
    for (int nt = 0; nt < 7; ++nt)                                            \
      acc[mt][nt] = __builtin_amdgcn_mfma_f32_16x16x32_bf16(                  \
          af_[mt], bf_[nt], acc[mt][nt], 0, 0, 0);                            \
  __builtin_amdgcn_s_setprio(0);                                              \
  WAITE;                                                                      \
  __builtin_amdgcn_s_barrier();                                               \
} while (0)

__global__ __launch_bounds__(512, 2) void conv_gemm(
    const unsigned short* __restrict__ Wr,
    const unsigned short* __restrict__ Xp,
    const float* __restrict__ bias,
    float* __restrict__ out) {
  extern __shared__ char smem[];   // 98304 B: buf{0,1,2} of (A 16K | B 16K)

  const int t    = threadIdx.x;
  const int lane = t & 63;
  const int wv   = t >> 6;        // 0..7
  const int wm   = wv >> 1;       // 0..3  co quarter (64)
  const int wn   = wv & 1;        // 0..1  px half (112)
  const int l15  = lane & 15;
  const int quad = lane >> 4;

  // T1: bijective XCD swizzle over 448 = 8 * 56 blocks
  const int bid = blockIdx.x;
  const int pb  = (bid & 7) * 56 + (bid >> 3);
  const int p0  = pb * BN;

  // staging map: thread t -> rows (t>>2, +128), phys chunk t&3,
  // logical chunk = (t&3) ^ ((row>>1)&3)  [T2 inverse on global source;
  // +128 preserves row bits 1..2 -> same XOR both sweeps]
  const int srow = t >> 2;                       // 0..127
  const int schk = (t & 3) ^ ((srow >> 1) & 3);

  const size_t aSrc0 = (size_t)srow * KTOT + schk * 8;
  const size_t aSrc1 = aSrc0 + (size_t)128 * KTOT;

  // B rows 0..255 (224 real + 32 pad rows reading harmless in-workspace bytes)
  const int pA = p0 + srow;
  const int pB = pA + 128;
  const int nA = pA / HWSZ;  const int hwA = pA - nA * HWSZ;
  const int hA = hwA / WW;   const int wA  = hwA - hA * WW;
  const int nB = pB / HWSZ;  const int hwB = pB - nB * HWSZ;
  const int hB = hwB / WW;   const int wB  = hwB - hB * WW;
  const size_t bSrc0 = ((size_t)((nA * HP + hA) * WP + wA)) * 256 + schk * 8;
  const size_t bSrc1 = ((size_t)((nB * HP + hB) * WP + wB)) * 256 + schk * 8;

  // read side: row*64 B; logical k-quad 'quad' -> phys chunk quad^((row>>1)&3)
  // (row bits 1..2 == l15 bits 1..2: all row bases are multiples of 16)
  const int rchk = (quad ^ ((l15 >> 1) & 3)) * 16;
  const int rdA  = (wm * 64  + l15) * 64 + rchk;   // + mt*1024
  const int rdB  = (wn * 112 + l15) * 64 + rchk;   // + nt*1024

  f32x4 acc[4][7];
  #pragma unroll
  for (int i = 0; i < 4; ++i)
    #pragma unroll
    for (int j = 0; j < 7; ++j)
      acc[i][j] = (f32x4){0.f, 0.f, 0.f, 0.f};

  // ---- prologue: stage tiles 0,1 into bufs 0,1; wait tile 0 (vmcnt(4))
  STAGE4(0, 0);
  STAGE4(1, 1);
  VM4;
  __builtin_amdgcn_s_barrier();

  // ---- main: 72 K-tiles of 32. Phase k: compute buf k%3, stage k+2 into
  // (k+2)%3, wait tile k+1 (vmcnt(4)). Buffers statically indexed (rule #20).
  #pragma unroll 1
  for (int it = 0; it < 23; ++it) {
    const int k0 = 3 * it;
    PHASE(0, VM4, STAGE4(2, k0 + 2));
    PHASE(1, VM4, STAGE4(0, k0 + 3));
    PHASE(2, VM4, STAGE4(1, k0 + 4));
  }
  PHASE(0, VM4, STAGE4(2, 71));    // k=69: stage last tile (71 -> buf 2)
  PHASE(1, VM0, NOWAIT);           // k=70: drain tile 71
  PHASE(2, NOWAIT, NOWAIT);        // k=71

  // ---- epilogue: C/D layout col = lane&15 (pixel), row = quad*4+reg (co)
  float bv[4][4];
  #pragma unroll
  for (int mt = 0; mt < 4; ++mt)
    #pragma unroll
    for (int r = 0; r < 4; ++r)
      bv[mt][r] = bias[wm * 64 + mt * 16 + quad * 4 + r];

  #pragma unroll
  for (int nt = 0; nt < 7; ++nt) {
    const int p  = p0 + wn * 112 + nt * 16 + l15;
    const int np = p / HWSZ;
    const int hw = p - np * HWSZ;
    const size_t obase = (size_t)np * (COUT * HWSZ) + hw;
    #pragma unroll
    for (int mt = 0; mt < 4; ++mt) {
      const int co = wm * 64 + mt * 16 + quad * 4;
      #pragma unroll
      for (int r = 0; r < 4; ++r)
        out[obase + (size_t)(co + r) * HWSZ] = acc[mt][nt][r] + bv[mt][r];
    }
  }
}

extern "C" void kernel_launch(void* const* d_in, const int* in_sizes, int n_in,
                              void* d_out, int out_size, void* d_ws, size_t ws_size,
                              hipStream_t stream) {
  const float* x    = (const float*)d_in[0];
  const float* w    = (const float*)d_in[1];
  const float* bias = (const float*)d_in[2];
  float* out        = (float*)d_out;

  // workspace layout: Xp (padded NHWC bf16) then Wr (reordered ternary bf16)
  unsigned short* xp = (unsigned short*)d_ws;                       // 55,115,776 B
  unsigned short* wr = (unsigned short*)((char*)d_ws + 55115776);   //  1,179,648 B

  prep<<<dim3(QBLKS + BATCH * HP * 4), dim3(256), 0, stream>>>(w, wr, x, xp);

  (void)hipFuncSetAttribute((const void*)conv_gemm,
                            hipFuncAttributeMaxDynamicSharedMemorySize, 98304);
  conv_gemm<<<dim3(NBLK), dim3(512), 98304, stream>>>(wr, xp, bias, out);
}

// Round 7
// 308.005 us; speedup vs baseline: 1.0885x; 1.0523x over previous
//
#include <hip/hip_runtime.h>

#define CIN   256
#define COUT  256
#define HH    56
#define WW    56
#define BATCH 32
#define KTOT  2304           // CIN * 9, ordered (kh,kw,ci)
#define HP    58
#define WP    58
#define NPIX  (BATCH*HH*WW)  // 100352
#define HWSZ  (HH*WW)        // 3136
#define BN    224            // pixel tile -> 448 blocks
#define NBLK  (NPIX/BN)      // 448

typedef __bf16 bf16x8 __attribute__((ext_vector_type(8)));
typedef float  f32x4  __attribute__((ext_vector_type(4)));

#define AS1 __attribute__((address_space(1)))
#define AS3 __attribute__((address_space(3)))

__device__ __forceinline__ unsigned short f2bf(float f) {
  union { float f; unsigned int u; } v; v.f = f;
  unsigned int u = v.u;
  u += 0x7fffu + ((u >> 16) & 1u);   // round-to-nearest-even
  return (unsigned short)(u >> 16);
}

__device__ __forceinline__ void async16(const void* g, void* l) {
  __builtin_amdgcn_global_load_lds((const AS1 unsigned int*)g,
                                   (AS3 unsigned int*)l, 16, 0, 0);
}

// ---- kernel 1 (fused): blocks [0,2304) quantize weights; rest do pad/NHWC.
#define TSTR 60
#define QBLKS 2304
__global__ __launch_bounds__(256) void prep(const float* __restrict__ w,
                                            unsigned short* __restrict__ wr,
                                            const float* __restrict__ x,
                                            unsigned short* __restrict__ xp) {
  const int bx = blockIdx.x;
  if (bx < QBLKS) {
    int tid = bx * 256 + threadIdx.x;       // < COUT*KTOT = 589824
    int co  = tid / KTOT;
    int rem = tid - co * KTOT;
    int tap = rem >> 8;          // kh*3+kw
    int ci  = rem & 255;
    int kh  = tap / 3;
    int kw  = tap - kh * 3;
    float v = w[((co * CIN + ci) * 3 + kh) * 3 + kw];
    float q = (fabsf(v) > 0.05f) ? ((v > 0.f) ? 1.f : -1.f) : 0.f;
    wr[tid] = f2bf(q);           // -1/0/+1 exact in bf16
    return;
  }
  const int pbx = bx - QBLKS;            // [0, 1856*4)
  const int nhp = pbx >> 2;              // n*58 + hp
  const int n   = nhp / HP;
  const int hp  = nhp - n * HP;
  const int ci0 = (pbx & 3) << 6;
  const int t   = threadIdx.x;
  const size_t obase = (size_t)nhp * (WP * 256);

  __shared__ __align__(16) float tile[64 * TSTR];
  const bool hborder = (hp == 0) || (hp == HP - 1);

  if (!hborder) {
    const int h = hp - 1;
    #pragma unroll
    for (int it = 0; it < 4; ++it) {
      int linear = it * 256 + t;
      if (linear < 896) {                // 64 ch x 14 float4
        int cil = linear / 14;
        int w4  = linear - cil * 14;
        *(float4*)&tile[cil * TSTR + w4 * 4] =
            *(const float4*)&x[(((size_t)(n * CIN + ci0 + cil)) * HH + h) * WW + w4 * 4];
      }
    }
  }
  __syncthreads();

  #pragma unroll
  for (int it = 0; it < 2; ++it) {               // 58*8 = 464 16B-chunks
    int linear = it * 256 + t;
    if (linear < 464) {
      int wp = linear >> 3;
      int g  = linear & 7;                       // ci group of 8
      unsigned int pk[4] = {0u, 0u, 0u, 0u};
      if (!hborder && wp != 0 && wp != WP - 1) {
        #pragma unroll
        for (int j = 0; j < 4; ++j) {
          int jr = (j + g) & 3;                  // bank-rotation (2-way, free)
          unsigned int lo = f2bf(tile[(g * 8 + 2 * jr) * TSTR + (wp - 1)]);
          unsigned int hi = f2bf(tile[(g * 8 + 2 * jr + 1) * TSTR + (wp - 1)]);
          pk[jr] = lo | (hi << 16);
        }
      }
      uint4 v; v.x = pk[0]; v.y = pk[1]; v.z = pk[2]; v.w = pk[3];
      *(uint4*)(xp + obase + (size_t)wp * 256 + ci0 + g * 8) = v;
    }
  }
}

// ---- kernel 2: implicit GEMM, 256co x 224px, BK=32, 8 waves (4Mx2N).
// ROUND-7 RESTRUCTURE (un-pin the scheduler):
//   r6 measured 2267 cyc/phase = MFMA-issue 1086 + LDS-read ~1050 + slop:
//   the forced {barrier; lgkmcnt(0); sched_barrier} SERIALIZED reads vs
//   MFMAs. Reads here are plain C++ loads -> the compiler emits fine
//   counted lgkmcnt (m97 evidence) and pipelines reads under MFMA clusters.
//   - ONE barrier per phase. Hazard proof: reads of buf b (phase k) are
//     consumed in-register before the wave reaches bar(k) (sched_barrier(0)
//     after the barrier pins everything inside the phase); the overwrite of
//     buf b is ISSUED only after bar(k) (phase k+1's STAGE4, program-order
//     vs asm memory clobbers); staging-ready is guaranteed by VM4 (counted:
//     8 in flight -> 4) before bar(k-1).
//   - no setprio (no wave role-split in this lockstep structure; T5 null
//     regime), no forced lgkmcnt.
//   - triple-buffered 96 KiB, dist-2 prefetch, counted VM4 (r5/r6 proven);
//     r3-verified conflict-free XOR swizzle chunk^=(row>>1)&3 both sides.

#define NOWAIT (void)0
#define VM4 asm volatile("s_waitcnt vmcnt(4)" ::: "memory")
#define VM0 asm volatile("s_waitcnt vmcnt(0)" ::: "memory")

// stage K-tile kn_ (A 16 KB + B 16 KB) into buffer buf_: 4 global_load_lds
#define STAGE4(buf_, kn_) do {                                                \
  const int kn__ = (kn_);                                                     \
  const size_t koW_ = (size_t)kn__ << 5;                                      \
  const int tap_ = kn__ >> 3;                                                 \
  const int kh_  = tap_ / 3;                                                  \
  const int kw_  = tap_ - kh_ * 3;                                            \
  const size_t koX_ = (size_t)((kh_ * WP + kw_) * 256 + ((kn__ & 7) << 5));   \
  char* da_ = smem + (buf_) * 32768 + t * 16;                                 \
  char* db_ = smem + (buf_) * 32768 + 16384 + t * 16;                         \
  async16(Wr + koW_ + aSrc0, da_);                                            \
  async16(Wr + koW_ + aSrc1, da_ + 8192);                                     \
  async16(Xp + koX_ + bSrc0, db_);                                            \
  async16(Xp + koX_ + bSrc1, db_ + 8192);                                     \
} while (0)

// one phase: stage-next (VMEM issue early), reads + MFMAs (compiler
// interleaves with counted lgkmcnt), counted vmem wait, ONE barrier.
#define PHASE(buf_, WAITE, ...) do {                                          \
  __VA_ARGS__;                                                                \
  bf16x8 af_[4], bf_[7];                                                      \
  _Pragma("unroll")                                                           \
  for (int mt = 0; mt < 4; ++mt)                                              \
    af_[mt] = *(const bf16x8*)(smem + (buf_) * 32768 + rdA + mt * 1024);      \
  _Pragma("unroll")                                                           \
  for (int nt = 0; nt < 7; ++nt)                                              \
    bf_[nt] = *(const bf16x8*)(smem + (buf_) * 32768 + 16384 + rdB + nt * 1024);\
  _Pragma("unroll")                                                           \
  for (int mt = 0; mt < 4; ++mt)                                              \
    _Pragma("unroll")                                                         \
    for (int nt = 0; nt < 7; ++nt)                                            \
      acc[mt][nt] = __builtin_amdgcn_mfma_f32_16x16x32_bf16(                  \
          af_[mt], bf_[nt], acc[mt][nt], 0, 0, 0);                            \
  WAITE;                                                                      \
  __builtin_amdgcn_s_barrier();                                               \
  __builtin_amdgcn_sched_barrier(0);                                          \
} while (0)

__global__ __launch_bounds__(512, 2) void conv_gemm(
    const unsigned short* __restrict__ Wr,
    const unsigned short* __restrict__ Xp,
    const float* __restrict__ bias,
    float* __restrict__ out) {
  extern __shared__ char smem[];   // 98304 B: buf{0,1,2} of (A 16K | B 16K)

  const int t    = threadIdx.x;
  const int lane = t & 63;
  const int wv   = t >> 6;        // 0..7
  const int wm   = wv >> 1;       // 0..3  co quarter (64)
  const int wn   = wv & 1;        // 0..1  px half (112)
  const int l15  = lane & 15;
  const int quad = lane >> 4;

  // T1: bijective XCD swizzle over 448 = 8 * 56 blocks
  const int bid = blockIdx.x;
  const int pb  = (bid & 7) * 56 + (bid >> 3);
  const int p0  = pb * BN;

  // staging map: thread t -> rows (t>>2, +128), phys chunk t&3,
  // logical chunk = (t&3) ^ ((row>>1)&3)  [T2 inverse on global source;
  // +128 preserves row bits 1..2 -> same XOR both sweeps]
  const int srow = t >> 2;                       // 0..127
  const int schk = (t & 3) ^ ((srow >> 1) & 3);

  const size_t aSrc0 = (size_t)srow * KTOT + schk * 8;
  const size_t aSrc1 = aSrc0 + (size_t)128 * KTOT;

  // B rows 0..255 (224 real + 32 pad rows reading harmless in-workspace bytes)
  const int pA = p0 + srow;
  const int pB = pA + 128;
  const int nA = pA / HWSZ;  const int hwA = pA - nA * HWSZ;
  const int hA = hwA / WW;   const int wA  = hwA - hA * WW;
  const int nB = pB / HWSZ;  const int hwB = pB - nB * HWSZ;
  const int hB = hwB / WW;   const int wB  = hwB - hB * WW;
  const size_t bSrc0 = ((size_t)((nA * HP + hA) * WP + wA)) * 256 + schk * 8;
  const size_t bSrc1 = ((size_t)((nB * HP + hB) * WP + wB)) * 256 + schk * 8;

  // read side: row*64 B; logical k-quad 'quad' -> phys chunk quad^((row>>1)&3)
  // (row bits 1..2 == l15 bits 1..2: all row bases are multiples of 16)
  const int rchk = (quad ^ ((l15 >> 1) & 3)) * 16;
  const int rdA  = (wm * 64  + l15) * 64 + rchk;   // + mt*1024
  const int rdB  = (wn * 112 + l15) * 64 + rchk;   // + nt*1024

  f32x4 acc[4][7];
  #pragma unroll
  for (int i = 0; i < 4; ++i)
    #pragma unroll
    for (int j = 0; j < 7; ++j)
      acc[i][j] = (f32x4){0.f, 0.f, 0.f, 0.f};

  // ---- prologue: stage tiles 0,1 into bufs 0,1; wait tile 0 (vmcnt(4))
  STAGE4(0, 0);
  STAGE4(1, 1);
  VM4;
  __builtin_amdgcn_s_barrier();
  __builtin_amdgcn_sched_barrier(0);

  // ---- main: 72 K-tiles of 32. Phase k: compute buf k%3, stage k+2 into
  // (k+2)%3, wait tile k+1 (VM4: 8 in flight -> 4). Static buffers (rule #20).
  #pragma unroll 1
  for (int it = 0; it < 23; ++it) {
    const int k0 = 3 * it;
    PHASE(0, VM4, STAGE4(2, k0 + 2));
    PHASE(1, VM4, STAGE4(0, k0 + 3));
    PHASE(2, VM4, STAGE4(1, k0 + 4));
  }
  PHASE(0, VM4, STAGE4(2, 71));    // k=69: stage last tile (71 -> buf 2)
  PHASE(1, VM0, NOWAIT);           // k=70: drain tile 71
  PHASE(2, NOWAIT, NOWAIT);        // k=71

  // ---- epilogue: C/D layout col = lane&15 (pixel), row = quad*4+reg (co)
  float bv[4][4];
  #pragma unroll
  for (int mt = 0; mt < 4; ++mt)
    #pragma unroll
    for (int r = 0; r < 4; ++r)
      bv[mt][r] = bias[wm * 64 + mt * 16 + quad * 4 + r];

  #pragma unroll
  for (int nt = 0; nt < 7; ++nt) {
    const int p  = p0 + wn * 112 + nt * 16 + l15;
    const int np = p / HWSZ;
    const int hw = p - np * HWSZ;
    const size_t obase = (size_t)np * (COUT * HWSZ) + hw;
    #pragma unroll
    for (int mt = 0; mt < 4; ++mt) {
      const int co = wm * 64 + mt * 16 + quad * 4;
      #pragma unroll
      for (int r = 0; r < 4; ++r)
        out[obase + (size_t)(co + r) * HWSZ] = acc[mt][nt][r] + bv[mt][r];
    }
  }
}

extern "C" void kernel_launch(void* const* d_in, const int* in_sizes, int n_in,
                              void* d_out, int out_size, void* d_ws, size_t ws_size,
                              hipStream_t stream) {
  const float* x    = (const float*)d_in[0];
  const float* w    = (const float*)d_in[1];
  const float* bias = (const float*)d_in[2];
  float* out        = (float*)d_out;

  // workspace layout: Xp (padded NHWC bf16) then Wr (reordered ternary bf16)
  unsigned short* xp = (unsigned short*)d_ws;                       // 55,115,776 B
  unsigned short* wr = (unsigned short*)((char*)d_ws + 55115776);   //  1,179,648 B

  prep<<<dim3(QBLKS + BATCH * HP * 4), dim3(256), 0, stream>>>(w, wr, x, xp);

  (void)hipFuncSetAttribute((const void*)conv_gemm,
                            hipFuncAttributeMaxDynamicSharedMemorySize, 98304);
  conv_gemm<<<dim3(NBLK), dim3(512), 98304, stream>>>(wr, xp, bias, out);
}

// Round 8
// 307.543 us; speedup vs baseline: 1.0901x; 1.0015x over previous
//
#include <hip/hip_runtime.h>

#define CIN   256
#define COUT  256
#define HH    56
#define WW    56
#define BATCH 32
#define KTOT  2304           // CIN * 9, ordered (kh,kw,ci)
#define HP    58
#define WP    58
#define NPIX  (BATCH*HH*WW)  // 100352
#define HWSZ  (HH*WW)        // 3136
#define BN    224            // pixel tile -> 448 blocks
#define NBLK  (NPIX/BN)      // 448

typedef __bf16 bf16x8 __attribute__((ext_vector_type(8)));
typedef float  f32x4  __attribute__((ext_vector_type(4)));

#define AS1 __attribute__((address_space(1)))
#define AS3 __attribute__((address_space(3)))

__device__ __forceinline__ unsigned short f2bf(float f) {
  union { float f; unsigned int u; } v; v.f = f;
  unsigned int u = v.u;
  u += 0x7fffu + ((u >> 16) & 1u);   // round-to-nearest-even
  return (unsigned short)(u >> 16);
}

__device__ __forceinline__ void async16(const void* g, void* l) {
  __builtin_amdgcn_global_load_lds((const AS1 unsigned int*)g,
                                   (AS3 unsigned int*)l, 16, 0, 0);
}

// ---- kernel 1 (fused): blocks [0,2304) quantize weights; rest do pad/NHWC.
#define TSTR 60
#define QBLKS 2304
__global__ __launch_bounds__(256) void prep(const float* __restrict__ w,
                                            unsigned short* __restrict__ wr,
                                            const float* __restrict__ x,
                                            unsigned short* __restrict__ xp) {
  const int bx = blockIdx.x;
  if (bx < QBLKS) {
    int tid = bx * 256 + threadIdx.x;       // < COUT*KTOT = 589824
    int co  = tid / KTOT;
    int rem = tid - co * KTOT;
    int tap = rem >> 8;          // kh*3+kw
    int ci  = rem & 255;
    int kh  = tap / 3;
    int kw  = tap - kh * 3;
    float v = w[((co * CIN + ci) * 3 + kh) * 3 + kw];
    float q = (fabsf(v) > 0.05f) ? ((v > 0.f) ? 1.f : -1.f) : 0.f;
    wr[tid] = f2bf(q);           // -1/0/+1 exact in bf16
    return;
  }
  const int pbx = bx - QBLKS;            // [0, 1856*4)
  const int nhp = pbx >> 2;              // n*58 + hp
  const int n   = nhp / HP;
  const int hp  = nhp - n * HP;
  const int ci0 = (pbx & 3) << 6;
  const int t   = threadIdx.x;
  const size_t obase = (size_t)nhp * (WP * 256);

  __shared__ __align__(16) float tile[64 * TSTR];
  const bool hborder = (hp == 0) || (hp == HP - 1);

  if (!hborder) {
    const int h = hp - 1;
    #pragma unroll
    for (int it = 0; it < 4; ++it) {
      int linear = it * 256 + t;
      if (linear < 896) {                // 64 ch x 14 float4
        int cil = linear / 14;
        int w4  = linear - cil * 14;
        *(float4*)&tile[cil * TSTR + w4 * 4] =
            *(const float4*)&x[(((size_t)(n * CIN + ci0 + cil)) * HH + h) * WW + w4 * 4];
      }
    }
  }
  __syncthreads();

  #pragma unroll
  for (int it = 0; it < 2; ++it) {               // 58*8 = 464 16B-chunks
    int linear = it * 256 + t;
    if (linear < 464) {
      int wp = linear >> 3;
      int g  = linear & 7;                       // ci group of 8
      unsigned int pk[4] = {0u, 0u, 0u, 0u};
      if (!hborder && wp != 0 && wp != WP - 1) {
        #pragma unroll
        for (int j = 0; j < 4; ++j) {
          int jr = (j + g) & 3;                  // bank-rotation (2-way, free)
          unsigned int lo = f2bf(tile[(g * 8 + 2 * jr) * TSTR + (wp - 1)]);
          unsigned int hi = f2bf(tile[(g * 8 + 2 * jr + 1) * TSTR + (wp - 1)]);
          pk[jr] = lo | (hi << 16);
        }
      }
      uint4 v; v.x = pk[0]; v.y = pk[1]; v.z = pk[2]; v.w = pk[3];
      *(uint4*)(xp + obase + (size_t)wp * 256 + ci0 + g * 8) = v;
    }
  }
}

// ---- kernel 2: implicit GEMM, 256co x 224px, BK=32, 8 waves (4Mx2N).
// ROUND-8 RESTRUCTURE (decouple LDS reads from MFMAs):
//   r7 measured 2047 cyc/phase = MFMA 1086 + LDS-read 1056 SERIAL: this
//   phase's MFMAs depend on this phase's reads, so the pipes alternate.
//   Fix: register fragment double-buffer for B. QUAD-buffered LDS (4x32 KB,
//   dist-3 staging) so tile k+1 is resident+drained when phase k starts;
//   phase k reads bf(k+1) into the alternate reg set (no consumer this
//   phase) while MFMAs of tile k run on the previous phase's set. Only the
//   4 A-reads stay in-phase (program order A-then-B -> compiler's counted
//   lgkmcnt(10..7) is nearly free).
//   Ledger (4 loads/stage): phase k stages k+3; at VM4, outstanding =
//   stage(k+3)+stage(k+2)=8 -> drains stage(k+2): tile k+1 was drained at
//   VM4@k-1 -> bf(k+1) reads in phase k are safe. Overwrite of buf (k-1)%4
//   by stage(k+3): that buffer's af reads completed (counted lgkm) before
//   their wave reached bar(k-1), which precedes the stage issue. Drain:
//   VM4@68 (tile 70), VM0@69 (tile 71), free after.
//   Registers: +28 VGPR (bf pair) -> ~132 VGPR + 112 acc < 256: keeps
//   2 waves/SIMD.

#define NOWAIT (void)0
#define VM4 asm volatile("s_waitcnt vmcnt(4)" ::: "memory")
#define VM0 asm volatile("s_waitcnt vmcnt(0)" ::: "memory")

// stage K-tile kn_ (A 16 KB + B 16 KB) into buffer buf_ (0..3)
#define STAGE4(buf_, kn_) do {                                                \
  const int kn__ = (kn_);                                                     \
  const size_t koW_ = (size_t)kn__ << 5;                                      \
  const int tap_ = kn__ >> 3;                                                 \
  const int kh_  = tap_ / 3;                                                  \
  const int kw_  = tap_ - kh_ * 3;                                            \
  const size_t koX_ = (size_t)((kh_ * WP + kw_) * 256 + ((kn__ & 7) << 5));   \
  char* da_ = smem + (buf_) * 32768 + t * 16;                                 \
  char* db_ = smem + (buf_) * 32768 + 16384 + t * 16;                         \
  async16(Wr + koW_ + aSrc0, da_);                                            \
  async16(Wr + koW_ + aSrc1, da_ + 8192);                                     \
  async16(Xp + koX_ + bSrc0, db_);                                            \
  async16(Xp + koX_ + bSrc1, db_ + 8192);                                     \
} while (0)

// phase k: stage(k+3) -> read af(k) from bc_ -> read bf(k+1) from bn_ into
// nxt_ -> 28 MFMAs on af x cur_ (pre-loaded last phase) -> counted wait ->
// barrier. Reads and MFMAs are independent => compiler overlaps the pipes.
#define PHASE(bc_, bn_, cur_, nxt_, DOBF_, WAITE, ...) do {                   \
  __VA_ARGS__;                                                                \
  bf16x8 af_[4];                                                              \
  _Pragma("unroll")                                                           \
  for (int mt = 0; mt < 4; ++mt)                                              \
    af_[mt] = *(const bf16x8*)(smem + (bc_) * 32768 + rdA + mt * 1024);       \
  if (DOBF_) {                                                                \
    _Pragma("unroll")                                                         \
    for (int nt = 0; nt < 7; ++nt)                                            \
      nxt_[nt] = *(const bf16x8*)(smem + (bn_) * 32768 + 16384 + rdB + nt * 1024);\
  }                                                                           \
  _Pragma("unroll")                                                           \
  for (int mt = 0; mt < 4; ++mt)                                              \
    _Pragma("unroll")                                                         \
    for (int nt = 0; nt < 7; ++nt)                                            \
      acc[mt][nt] = __builtin_amdgcn_mfma_f32_16x16x32_bf16(                  \
          af_[mt], cur_[nt], acc[mt][nt], 0, 0, 0);                           \
  WAITE;                                                                      \
  __builtin_amdgcn_s_barrier();                                               \
  __builtin_amdgcn_sched_barrier(0);                                          \
} while (0)

__global__ __launch_bounds__(512, 2) void conv_gemm(
    const unsigned short* __restrict__ Wr,
    const unsigned short* __restrict__ Xp,
    const float* __restrict__ bias,
    float* __restrict__ out) {
  extern __shared__ char smem[];   // 131072 B: buf{0..3} of (A 16K | B 16K)

  const int t    = threadIdx.x;
  const int lane = t & 63;
  const int wv   = t >> 6;        // 0..7
  const int wm   = wv >> 1;       // 0..3  co quarter (64)
  const int wn   = wv & 1;        // 0..1  px half (112)
  const int l15  = lane & 15;
  const int quad = lane >> 4;

  // T1: bijective XCD swizzle over 448 = 8 * 56 blocks
  const int bid = blockIdx.x;
  const int pb  = (bid & 7) * 56 + (bid >> 3);
  const int p0  = pb * BN;

  // staging map: thread t -> rows (t>>2, +128), phys chunk t&3,
  // logical chunk = (t&3) ^ ((row>>1)&3)  [T2 inverse on global source]
  const int srow = t >> 2;                       // 0..127
  const int schk = (t & 3) ^ ((srow >> 1) & 3);

  const size_t aSrc0 = (size_t)srow * KTOT + schk * 8;
  const size_t aSrc1 = aSrc0 + (size_t)128 * KTOT;

  // B rows 0..255 (224 real + 32 pad rows reading harmless in-workspace bytes)
  const int pA = p0 + srow;
  const int pB = pA + 128;
  const int nA = pA / HWSZ;  const int hwA = pA - nA * HWSZ;
  const int hA = hwA / WW;   const int wA  = hwA - hA * WW;
  const int nB = pB / HWSZ;  const int hwB = pB - nB * HWSZ;
  const int hB = hwB / WW;   const int wB  = hwB - hB * WW;
  const size_t bSrc0 = ((size_t)((nA * HP + hA) * WP + wA)) * 256 + schk * 8;
  const size_t bSrc1 = ((size_t)((nB * HP + hB) * WP + wB)) * 256 + schk * 8;

  // read side: row*64 B; logical k-quad 'quad' -> phys chunk quad^((row>>1)&3)
  const int rchk = (quad ^ ((l15 >> 1) & 3)) * 16;
  const int rdA  = (wm * 64  + l15) * 64 + rchk;   // + mt*1024
  const int rdB  = (wn * 112 + l15) * 64 + rchk;   // + nt*1024

  f32x4 acc[4][7];
  #pragma unroll
  for (int i = 0; i < 4; ++i)
    #pragma unroll
    for (int j = 0; j < 7; ++j)
      acc[i][j] = (f32x4){0.f, 0.f, 0.f, 0.f};

  bf16x8 bfA[7], bfB[7];           // register-double-buffered B fragments

  // ---- prologue: stage tiles 0,1,2 into bufs 0,1,2; drain 0 AND 1 (VM4
  // with 12 outstanding -> 4); pre-read bf(0) into set A.
  STAGE4(0, 0);
  STAGE4(1, 1);
  STAGE4(2, 2);
  VM4;
  __builtin_amdgcn_s_barrier();
  __builtin_amdgcn_sched_barrier(0);
  #pragma unroll
  for (int nt = 0; nt < 7; ++nt)
    bfA[nt] = *(const bf16x8*)(smem + 16384 + rdB + nt * 1024);

  // ---- main: k = 0..67 (17 x 4 phases); buffers cycle %4, bf sets by parity
  #pragma unroll 1
  for (int it = 0; it < 17; ++it) {
    const int k0 = 4 * it;
    PHASE(0, 1, bfA, bfB, 1, VM4, STAGE4(3, k0 + 3));
    PHASE(1, 2, bfB, bfA, 1, VM4, STAGE4(0, k0 + 4));
    PHASE(2, 3, bfA, bfB, 1, VM4, STAGE4(1, k0 + 5));
    PHASE(3, 0, bfB, bfA, 1, VM4, STAGE4(2, k0 + 6));
  }
  // ---- peeled drain: k = 68..71
  PHASE(0, 1, bfA, bfB, 1, VM4, STAGE4(3, 71));   // k=68: stage last tile
  PHASE(1, 2, bfB, bfA, 1, VM0, NOWAIT);          // k=69: drain tile 71
  PHASE(2, 3, bfA, bfB, 1, NOWAIT, NOWAIT);       // k=70: bf(71) from buf 3
  PHASE(3, 0, bfB, bfA, 0, NOWAIT, NOWAIT);       // k=71: no bf read

  // ---- epilogue: C/D layout col = lane&15 (pixel), row = quad*4+reg (co)
  float bv[4][4];
  #pragma unroll
  for (int mt = 0; mt < 4; ++mt)
    #pragma unroll
    for (int r = 0; r < 4; ++r)
      bv[mt][r] = bias[wm * 64 + mt * 16 + quad * 4 + r];

  #pragma unroll
  for (int nt = 0; nt < 7; ++nt) {
    const int p  = p0 + wn * 112 + nt * 16 + l15;
    const int np = p / HWSZ;
    const int hw = p - np * HWSZ;
    const size_t obase = (size_t)np * (COUT * HWSZ) + hw;
    #pragma unroll
    for (int mt = 0; mt < 4; ++mt) {
      const int co = wm * 64 + mt * 16 + quad * 4;
      #pragma unroll
      for (int r = 0; r < 4; ++r)
        out[obase + (size_t)(co + r) * HWSZ] = acc[mt][nt][r] + bv[mt][r];
    }
  }
}

extern "C" void kernel_launch(void* const* d_in, const int* in_sizes, int n_in,
                              void* d_out, int out_size, void* d_ws, size_t ws_size,
                              hipStream_t stream) {
  const float* x    = (const float*)d_in[0];
  const float* w    = (const float*)d_in[1];
  const float* bias = (const float*)d_in[2];
  float* out        = (float*)d_out;

  // workspace layout: Xp (padded NHWC bf16) then Wr (reordered ternary bf16)
  unsigned short* xp = (unsigned short*)d_ws;                       // 55,115,776 B
  unsigned short* wr = (unsigned short*)((char*)d_ws + 55115776);   //  1,179,648 B

  prep<<<dim3(QBLKS + BATCH * HP * 4), dim3(256), 0, stream>>>(w, wr, x, xp);

  (void)hipFuncSetAttribute((const void*)conv_gemm,
                            hipFuncAttributeMaxDynamicSharedMemorySize, 131072);
  conv_gemm<<<dim3(NBLK), dim3(512), 131072, stream>>>(wr, xp, bias, out);
}